// Round 3
// baseline (1301.631 us; speedup 1.0000x reference)
//
#include <hip/hip_runtime.h>
#include <stdint.h>

typedef __bf16 bf16;
typedef __attribute__((ext_vector_type(8))) __bf16 bf16x8;
typedef __attribute__((ext_vector_type(4))) float f32x4;

#define T_TOK 4096
#define DIM   1536
#define NE    64
#define HD    384
#define TOPK  8
#define CAP   1024
#define TK    32768   // T_TOK*TOPK

// ---------------- fused router: fp32 logits -> softmax -> top8 -> renorm ----------------
// 16 tokens per block; x rows staged in LDS; wave wv computes experts wv*16..wv*16+15.
__global__ __launch_bounds__(256) void router_k(const float* __restrict__ x, const float* __restrict__ gw,
                                                int* __restrict__ sel, float* __restrict__ wts,
                                                int* __restrict__ counts) {
    __shared__ float xs[16][DIM];     // 98304 B
    __shared__ float lgs[16][NE];     // 4096 B
    int t0 = blockIdx.x * 16;
    int tid = threadIdx.x;
    {
        const float4* src = (const float4*)(x + (size_t)t0 * DIM);
        float4* dst = (float4*)&xs[0][0];
        for (int i = tid; i < 16 * DIM / 4; i += 256) dst[i] = src[i];
    }
    __syncthreads();
    int lane = tid & 63, wv = tid >> 6;
    for (int ee = 0; ee < 16; ++ee) {
        int e = wv * 16 + ee;
        const float2* g2 = (const float2*)(gw + (size_t)e * DIM);
        float acc[16];
        #pragma unroll
        for (int t = 0; t < 16; ++t) acc[t] = 0.f;
        #pragma unroll
        for (int it = 0; it < DIM / 128; ++it) {
            float2 gv = g2[lane + 64 * it];
            #pragma unroll
            for (int t = 0; t < 16; ++t) {
                float2 xv = *(const float2*)&xs[t][2 * (lane + 64 * it)];
                acc[t] += gv.x * xv.x + gv.y * xv.y;
            }
        }
        #pragma unroll
        for (int t = 0; t < 16; ++t) {
            float a = acc[t];
            #pragma unroll
            for (int off = 32; off; off >>= 1) a += __shfl_xor(a, off, 64);
            if (lane == 0) lgs[t][e] = a;
        }
    }
    __syncthreads();
    // top-8 per token: wave wv handles tokens wv*4 .. wv*4+3
    for (int q = 0; q < 4; ++q) {
        int tt = wv * 4 + q;
        int t = t0 + tt;
        float l = lgs[tt][lane];
        float m = l;
        #pragma unroll
        for (int off = 32; off; off >>= 1) m = fmaxf(m, __shfl_xor(m, off, 64));
        float p = __expf(l - m);
        float s = p;
        #pragma unroll
        for (int off = 32; off; off >>= 1) s += __shfl_xor(s, off, 64);
        p /= s;
        float cur = p;
        float psum = 0.f;
        float myv = 0.f; int myi = 0;
        #pragma unroll
        for (int k = 0; k < 8; ++k) {
            float v = cur; int idx = lane;
            #pragma unroll
            for (int off = 32; off; off >>= 1) {
                float ov = __shfl_xor(v, off, 64);
                int   oi = __shfl_xor(idx, off, 64);
                if (ov > v || (ov == v && oi < idx)) { v = ov; idx = oi; }
            }
            psum += v;
            if (lane == k) { myv = v; myi = idx; }
            if (lane == idx) cur = -1.f;
        }
        if (lane < 8) {
            sel[t * TOPK + lane] = myi;
            wts[t * TOPK + lane] = myv / psum;   // ref keeps fp32 (hs.dtype == float32)
            atomicAdd(&counts[myi], 1);
        }
    }
}

// ---------------- exclusive scan over 64 counts (capped at CAP) ----------------
__global__ void scan_k(const int* __restrict__ counts, int* __restrict__ offsets) {
    if (threadIdx.x == 0) {
        int s = 0;
        for (int e = 0; e < NE; ++e) {
            offsets[e] = s;
            int c = counts[e]; if (c > CAP) c = CAP;
            s += c;
        }
        offsets[NE] = s;
    }
}

// ---------------- compact assignments by expert ----------------
__global__ __launch_bounds__(256) void dispatch_k(const int* __restrict__ sel, const float* __restrict__ wts,
                                                  const int* __restrict__ offsets, int* __restrict__ cursor,
                                                  int* __restrict__ rowtok, float* __restrict__ roww) {
    int i = blockIdx.x * 256 + threadIdx.x;
    if (i >= TK) return;
    int e = sel[i];
    int t = i >> 3;
    int p = atomicAdd(&cursor[e], 1);
    if (p < CAP) {
        int idx = offsets[e] + p;
        rowtok[idx] = t;
        roww[idx] = wts[i];
    }
}

__device__ __forceinline__ bf16x8 pack8(const float* f) {
    bf16x8 v;
    #pragma unroll
    for (int j = 0; j < 8; ++j) v[j] = (bf16)f[j];
    return v;
}

// ---------------- GEMM1: fused gate+up (fp32 in, bf16 MFMA), SwiGLU -> Abuf (bf16) ----------------
// grid (8 mtiles, 3 ntiles, 64 experts), block 256 (4 waves, each 64x64)
__global__ __launch_bounds__(256) void gemm_gu_k(
        const float* __restrict__ x, const float* __restrict__ Wg, const float* __restrict__ Wu,
        const int* __restrict__ rowtok, const int* __restrict__ offsets, const int* __restrict__ counts,
        bf16* __restrict__ Abuf) {
    int e = blockIdx.z;
    int cnt = counts[e]; if (cnt > CAP) cnt = CAP;
    int m0 = blockIdx.x * 128;
    if (cnt == 0 || m0 >= cnt) return;
    int base = offsets[e];
    int n0 = blockIdx.y * 128;

    __shared__ __align__(16) bf16 As[128 * 32];
    __shared__ __align__(16) bf16 Bgs[128 * 32];
    __shared__ __align__(16) bf16 Bus[128 * 32];

    int tid = threadIdx.x;
    // A staging: thread owns row m0+arow, k-segment aseg..aseg+15 (fp32 -> bf16)
    int arow = tid >> 1, aseg = (tid & 1) * 16;
    int mrow = m0 + arow; if (mrow >= cnt) mrow = cnt - 1;
    const float* pA = x + (size_t)rowtok[base + mrow] * DIM + aseg;
    // B staging: thread owns column n = n0+bn, k-rows bk..bk+15
    int bn = tid & 127;
    int bk = (tid >> 7) * 16;
    const float* pG = Wg + ((size_t)e * DIM + bk) * HD + (n0 + bn);
    const float* pU = Wu + ((size_t)e * DIM + bk) * HD + (n0 + bn);

    int lane = tid & 63, wv = tid >> 6;
    int mo = (wv & 1) * 64, no = (wv >> 1) * 64;
    int fr = lane & 15, fq = lane >> 4;

    f32x4 ag[4][4], au[4][4];
    #pragma unroll
    for (int i = 0; i < 4; ++i)
        #pragma unroll
        for (int j = 0; j < 4; ++j)
            #pragma unroll
            for (int r = 0; r < 4; ++r) { ag[i][j][r] = 0.f; au[i][j][r] = 0.f; }

    for (int k0 = 0; k0 < DIM; k0 += 32) {
        float av[16] __attribute__((aligned(16)));
        float gv[16] __attribute__((aligned(16)));
        float uv[16] __attribute__((aligned(16)));
        *(float4*)&av[0]  = *(const float4*)(pA + k0);
        *(float4*)&av[4]  = *(const float4*)(pA + k0 + 4);
        *(float4*)&av[8]  = *(const float4*)(pA + k0 + 8);
        *(float4*)&av[12] = *(const float4*)(pA + k0 + 12);
        #pragma unroll
        for (int j = 0; j < 16; ++j) {
            gv[j] = pG[(size_t)(k0 + j) * HD];
            uv[j] = pU[(size_t)(k0 + j) * HD];
        }
        __syncthreads();
        *(bf16x8*)&As[arow * 32 + aseg]      = pack8(&av[0]);
        *(bf16x8*)&As[arow * 32 + aseg + 8]  = pack8(&av[8]);
        *(bf16x8*)&Bgs[bn * 32 + bk]         = pack8(&gv[0]);
        *(bf16x8*)&Bgs[bn * 32 + bk + 8]     = pack8(&gv[8]);
        *(bf16x8*)&Bus[bn * 32 + bk]         = pack8(&uv[0]);
        *(bf16x8*)&Bus[bn * 32 + bk + 8]     = pack8(&uv[8]);
        __syncthreads();
        bf16x8 af[4], bgf[4], buf_[4];
        #pragma unroll
        for (int i = 0; i < 4; ++i) {
            af[i]   = *(const bf16x8*)&As[(mo + i * 16 + fr) * 32 + fq * 8];
            bgf[i]  = *(const bf16x8*)&Bgs[(no + i * 16 + fr) * 32 + fq * 8];
            buf_[i] = *(const bf16x8*)&Bus[(no + i * 16 + fr) * 32 + fq * 8];
        }
        #pragma unroll
        for (int i = 0; i < 4; ++i)
            #pragma unroll
            for (int j = 0; j < 4; ++j) {
                ag[i][j] = __builtin_amdgcn_mfma_f32_16x16x32_bf16(af[i], bgf[j], ag[i][j], 0, 0, 0);
                au[i][j] = __builtin_amdgcn_mfma_f32_16x16x32_bf16(af[i], buf_[j], au[i][j], 0, 0, 0);
            }
    }
    #pragma unroll
    for (int i = 0; i < 4; ++i) {
        #pragma unroll
        for (int j = 0; j < 4; ++j) {
            int col = n0 + no + j * 16 + fr;
            #pragma unroll
            for (int r = 0; r < 4; ++r) {
                int gm = m0 + mo + i * 16 + fq * 4 + r;
                if (gm < cnt) {
                    float g = ag[i][j][r], u = au[i][j][r];
                    float sg = g / (1.f + __expf(-g));   // silu
                    Abuf[(size_t)(base + gm) * HD + col] = (bf16)(sg * u);
                }
            }
        }
    }
}

// ---------------- GEMM2: down projection (bf16 A, fp32 W), weighted atomic scatter -> out ----------------
// grid (8 mtiles, 12 ntiles, 64 experts)
__global__ __launch_bounds__(256) void gemm_dn_k(
        const bf16* __restrict__ Abuf, const float* __restrict__ Wd,
        const int* __restrict__ rowtok, const float* __restrict__ roww,
        const int* __restrict__ offsets, const int* __restrict__ counts,
        float* __restrict__ out) {
    int e = blockIdx.z;
    int cnt = counts[e]; if (cnt > CAP) cnt = CAP;
    int m0 = blockIdx.x * 128;
    if (cnt == 0 || m0 >= cnt) return;
    int base = offsets[e];
    int n0 = blockIdx.y * 128;

    __shared__ __align__(16) bf16 As[128 * 32];
    __shared__ __align__(16) bf16 Bs[128 * 32];

    int tid = threadIdx.x;
    int arow = tid >> 1, aseg = (tid & 1) * 16;
    int mrow = m0 + arow; if (mrow >= cnt) mrow = cnt - 1;
    const bf16* pA = Abuf + (size_t)(base + mrow) * HD + aseg;
    int bn = tid & 127;
    int bk = (tid >> 7) * 16;
    const float* pB = Wd + ((size_t)e * HD + bk) * DIM + (n0 + bn);

    int lane = tid & 63, wv = tid >> 6;
    int mo = (wv & 1) * 64, no = (wv >> 1) * 64;
    int fr = lane & 15, fq = lane >> 4;

    f32x4 acc[4][4];
    #pragma unroll
    for (int i = 0; i < 4; ++i)
        #pragma unroll
        for (int j = 0; j < 4; ++j)
            #pragma unroll
            for (int r = 0; r < 4; ++r) acc[i][j][r] = 0.f;

    for (int k0 = 0; k0 < HD; k0 += 32) {
        uint4 a0 = *(const uint4*)(pA + k0);
        uint4 a1 = *(const uint4*)(pA + k0 + 8);
        float bv[16] __attribute__((aligned(16)));
        #pragma unroll
        for (int j = 0; j < 16; ++j) bv[j] = pB[(size_t)(k0 + j) * DIM];
        __syncthreads();
        *(uint4*)&As[arow * 32 + aseg]     = a0;
        *(uint4*)&As[arow * 32 + aseg + 8] = a1;
        *(bf16x8*)&Bs[bn * 32 + bk]     = pack8(&bv[0]);
        *(bf16x8*)&Bs[bn * 32 + bk + 8] = pack8(&bv[8]);
        __syncthreads();
        bf16x8 af[4], bf[4];
        #pragma unroll
        for (int i = 0; i < 4; ++i) {
            af[i] = *(const bf16x8*)&As[(mo + i * 16 + fr) * 32 + fq * 8];
            bf[i] = *(const bf16x8*)&Bs[(no + i * 16 + fr) * 32 + fq * 8];
        }
        #pragma unroll
        for (int i = 0; i < 4; ++i)
            #pragma unroll
            for (int j = 0; j < 4; ++j)
                acc[i][j] = __builtin_amdgcn_mfma_f32_16x16x32_bf16(af[i], bf[j], acc[i][j], 0, 0, 0);
    }
    #pragma unroll
    for (int i = 0; i < 4; ++i) {
        #pragma unroll
        for (int r = 0; r < 4; ++r) {
            int gm = m0 + mo + i * 16 + fq * 4 + r;
            if (gm < cnt) {
                int tok = rowtok[base + gm];
                float w = roww[base + gm];
                float* po = out + (size_t)tok * DIM + n0 + no + fr;
                #pragma unroll
                for (int j = 0; j < 4; ++j)
                    atomicAdd(po + j * 16, acc[i][j][r] * w);
            }
        }
    }
}

extern "C" void kernel_launch(void* const* d_in, const int* in_sizes, int n_in,
                              void* d_out, int out_size, void* d_ws, size_t ws_size,
                              hipStream_t stream) {
    const float* x  = (const float*)d_in[0];
    const float* gw = (const float*)d_in[1];
    const float* Wg = (const float*)d_in[2];
    const float* Wu = (const float*)d_in[3];
    const float* Wd = (const float*)d_in[4];
    float* out = (float*)d_out;
    char* ws = (char*)d_ws;

    int*   counts  = (int*)(ws + 0);        // 64 ints
    int*   cursor  = (int*)(ws + 256);      // 64 ints
    int*   offsets = (int*)(ws + 512);      // 65 ints
    int*   sel     = (int*)(ws + 4096);                    // TK ints   (128 KB)
    float* wts     = (float*)(ws + 4096 + 1 * 131072);     // TK floats
    int*   rowtok  = (int*)(ws + 4096 + 2 * 131072);       // TK ints
    float* roww    = (float*)(ws + 4096 + 3 * 131072);     // TK floats
    bf16*  Abuf    = (bf16*)(ws + 4096 + 4 * 131072);      // TK*HD bf16 (25.2 MB)
    // total ws usage ~25.7 MB

    hipMemsetAsync(ws, 0, 1024, stream);                                  // counts + cursor
    hipMemsetAsync(d_out, 0, (size_t)out_size * sizeof(float), stream);   // combine accumulator
    router_k<<<T_TOK / 16, 256, 0, stream>>>(x, gw, sel, wts, counts);
    scan_k<<<1, 64, 0, stream>>>(counts, offsets);
    dispatch_k<<<TK / 256, 256, 0, stream>>>(sel, wts, offsets, cursor, rowtok, roww);
    gemm_gu_k<<<dim3(CAP / 128, HD / 128, NE), 256, 0, stream>>>(x, Wg, Wu, rowtok, offsets, counts, Abuf);
    gemm_dn_k<<<dim3(CAP / 128, DIM / 128, NE), 256, 0, stream>>>(Abuf, Wd, rowtok, roww, offsets, counts, out);
}